// Round 1
// baseline (402.796 us; speedup 1.0000x reference)
//
#include <hip/hip_runtime.h>

typedef __attribute__((ext_vector_type(8))) short bf16x8;
typedef __attribute__((ext_vector_type(4))) float f32x4;

__device__ __forceinline__ unsigned short f2bf(float f) {
  unsigned u = __builtin_bit_cast(unsigned, f);
  u += 0x7FFFu + ((u >> 16) & 1u);
  return (unsigned short)(u >> 16);
}

__device__ __forceinline__ unsigned long long pack4bf(f32x4 v) {
  unsigned long long r0 = f2bf(v[0]);
  unsigned long long r1 = f2bf(v[1]);
  unsigned long long r2 = f2bf(v[2]);
  unsigned long long r3 = f2bf(v[3]);
  return r0 | (r1 << 16) | (r2 << 32) | (r3 << 48);
}

// Fragmentize qkv_w (48 row-tiles of 16) + proj_w (16 row-tiles) to bf16 in ws.
// frag(rt,ks), lane l holds W[16*rt + (l&15)][32*ks + 8*(l>>4) + i], i=0..7.
// qkv frags at ws + g*1024 (g = rt*8+ks, g<384); proj frags at ws + (384+p)*1024.
__global__ void prep_weights(const float* __restrict__ qkv_w,
                             const float* __restrict__ proj_w,
                             unsigned char* __restrict__ ws) {
  int g = blockIdx.x;   // 0..511
  int l = threadIdx.x;  // 0..63
  int lr = l & 15, lg = l >> 4;
  const float* src;
  if (g < 384) {
    int rt = g >> 3, ks = g & 7;
    src = qkv_w + (size_t)(16 * rt + lr) * 256 + 32 * ks + 8 * lg;
  } else {
    int p = g - 384;
    int rt = p >> 3, ks = p & 7;
    src = proj_w + (size_t)(16 * rt + lr) * 256 + 32 * ks + 8 * lg;
  }
  f32x4 a = *(const f32x4*)(src);
  f32x4 b = *(const f32x4*)(src + 4);
  unsigned long long* dst = (unsigned long long*)(ws + (size_t)g * 1024 + l * 16);
  dst[0] = pack4bf(a);
  dst[1] = pack4bf(b);
}

// One block = one window. 8 waves (512 threads).
// LDS map (128 KiB):
//   [0,32K)    xs: bf16 x-tile [64][256], byte(r,c)= r*512 + ((2c)^((r&7)<<4));
//              reused in attention phase as per-wave P buffers (wave w: [w*4K,(w+1)*4K), [m][32] stride 64B)
//   [32K,64K)  q: [h][m][d] bf16, byte = h*4096 + m*64 + d*2
//   [64K,96K)  k: same layout; reused as ao [h][m][d] after k is consumed
//   [96K,128K) vT: [h][d][j] bf16, byte = h*4096 + d*128 + ((2j)^((d&7)<<4))
__global__ __launch_bounds__(512, 2)
void winattn_main(const float* __restrict__ x,
                  const float* __restrict__ mask,
                  const float* __restrict__ qkv_b,
                  const float* __restrict__ proj_b,
                  const float* __restrict__ bias_table,
                  const unsigned char* __restrict__ ws,
                  float* __restrict__ out) {
  __shared__ __align__(16) unsigned char lds[131072];
  const int tid = threadIdx.x;
  const int wv = tid >> 6;
  const int ln = tid & 63;
  const int lr = ln & 15, lg = ln >> 4;
  const int b = blockIdx.x;
  const int w = b & 63;  // mask/window index = b % nW

  // ---- Phase 1: stage x -> xs (bf16, swizzled), rows >= 49 zeroed
  {
    const int r = tid >> 3;
    const int c0 = (tid & 7) * 4;
    const float* xrow = x + ((size_t)b * 49 + r) * 256;
    unsigned char* row = lds + r * 512;
    const int swz = (r & 7) << 4;
#pragma unroll
    for (int u = 0; u < 8; ++u) {
      int c = c0 + 32 * u;
      f32x4 v = {0.f, 0.f, 0.f, 0.f};
      if (r < 49) v = *(const f32x4*)(xrow + c);
      *(unsigned long long*)(row + ((2 * c) ^ swz)) = pack4bf(v);
    }
  }
  __syncthreads();

  // ---- Phase 2: hold all 32 x fragments in VGPRs; QK-GEMM; V-GEMM
  bf16x8 xf[4][8];
#pragma unroll
  for (int tt = 0; tt < 4; ++tt) {
    int row = 16 * tt + lr;
    const unsigned char* rp = lds + row * 512;
    int swz = (row & 7) << 4;
#pragma unroll
    for (int ks = 0; ks < 8; ++ks)
      xf[tt][ks] = *(const bf16x8*)(rp + ((64 * ks + 16 * lg) ^ swz));
  }

  // QK-GEMM: C[ch][tok] = sum_c W[ch][c]*x[tok][c]; wave handles channel tiles 4wv..4wv+3
  {
    unsigned char* dst = lds + 32768 + ((wv < 4) ? 0 : 32768);
#pragma unroll
    for (int i = 0; i < 4; ++i) {
      const int mt = 4 * wv + i;  // 0..31 -> qkv_w rows 16mt.. (q: 0..255, k: 256..511)
      bf16x8 af[8];
#pragma unroll
      for (int ks = 0; ks < 8; ++ks)
        af[ks] = *(const bf16x8*)(ws + (size_t)(mt * 8 + ks) * 1024 + ln * 16);
      f32x4 bias;
#pragma unroll
      for (int r2 = 0; r2 < 4; ++r2) bias[r2] = qkv_b[16 * mt + 4 * lg + r2];
      const int chl = ((mt & 15) << 4) + 4 * lg;  // channel within q or k
      const int hq = chl >> 5;
      const int d0 = chl & 31;
#pragma unroll
      for (int tt = 0; tt < 4; ++tt) {
        f32x4 acc = {0.f, 0.f, 0.f, 0.f};
#pragma unroll
        for (int ks = 0; ks < 8; ++ks)
          acc = __builtin_amdgcn_mfma_f32_16x16x32_bf16(af[ks], xf[tt][ks], acc, 0, 0, 0);
        acc += bias;
        int m = lr + 16 * tt;
        *(unsigned long long*)(dst + hq * 4096 + m * 64 + d0 * 2) = pack4bf(acc);
      }
    }
  }

  // V-GEMM: C[tok][ch] = sum_c x[tok][c]*Wv[ch][c]; wave handles v-channel tiles {2wv,2wv+1} (= head wv)
  {
#pragma unroll
    for (int ni = 0; ni < 2; ++ni) {
      const int nt = 2 * wv + ni;  // 0..15
      bf16x8 bfr[8];
#pragma unroll
      for (int ks = 0; ks < 8; ++ks)
        bfr[ks] = *(const bf16x8*)(ws + (size_t)((32 + nt) * 8 + ks) * 1024 + ln * 16);
      const float vbias = qkv_b[512 + 16 * nt + lr];
      const int d = lr + 16 * (nt & 1);
      const int swz = (d & 7) << 4;
      unsigned char* vrow = lds + 98304 + wv * 4096 + d * 128;
#pragma unroll
      for (int mt = 0; mt < 4; ++mt) {
        f32x4 acc = {0.f, 0.f, 0.f, 0.f};
#pragma unroll
        for (int ks = 0; ks < 8; ++ks)
          acc = __builtin_amdgcn_mfma_f32_16x16x32_bf16(xf[mt][ks], bfr[ks], acc, 0, 0, 0);
        acc += vbias;
        int j0b = 32 * mt + 8 * lg;  // byte offset of j0 = 16mt+4lg
        *(unsigned long long*)(vrow + (j0b ^ swz)) = pack4bf(acc);
      }
    }
  }
  __syncthreads();

  // ---- Phase 3: attention, head h = wv (all LDS reads/writes head-private to this wave)
  {
    const int h = wv;
    const unsigned char* qb = lds + 32768 + h * 4096;
    const unsigned char* kb = lds + 65536 + h * 4096;
    const unsigned char* vb = lds + 98304 + h * 4096;
    bf16x8 qf[4], kf[4];
#pragma unroll
    for (int t = 0; t < 4; ++t) {
      int m = lr + 16 * t;
      qf[t] = *(const bf16x8*)(qb + m * 64 + lg * 16);
      kf[t] = *(const bf16x8*)(kb + m * 64 + lg * 16);
    }
    // S^T[j][m] = sum_d k[j][d] q[m][d]; frag (jt,mtc): lane holds j=16jt+4lg+r, m=lr+16mtc
    f32x4 s[4][4];
#pragma unroll
    for (int jt = 0; jt < 4; ++jt)
#pragma unroll
      for (int mtc = 0; mtc < 4; ++mtc) {
        f32x4 z = {0.f, 0.f, 0.f, 0.f};
        s[jt][mtc] = __builtin_amdgcn_mfma_f32_16x16x32_bf16(kf[jt], qf[mtc], z, 0, 0, 0);
      }
    const float scale = 0.17677669529663687f;  // 1/sqrt(32)
#pragma unroll
    for (int mtc = 0; mtc < 4; ++mtc) {
      const int m = lr + 16 * mtc;
      const int mm = (m < 49) ? m : 0;
      const int rm = (mm * 37) >> 8;  // mm/7
      const int cm = mm - 7 * rm;
      const float* mrow = mask + ((size_t)w * 49 + mm) * 49;
      float mx = -1e30f;
#pragma unroll
      for (int jt = 0; jt < 4; ++jt) {
#pragma unroll
        for (int r2 = 0; r2 < 4; ++r2) {
          int j = 16 * jt + 4 * lg + r2;
          float add;
          if (j < 49) {
            int rj = (j * 37) >> 8;
            int cj = j - 7 * rj;
            int rpi = (rm - rj + 6) * 13 + (cm - cj + 6);
            add = mrow[j] + bias_table[rpi * 8 + h];
          } else {
            add = -1e30f;
          }
          float val = s[jt][mtc][r2] * scale + add;
          s[jt][mtc][r2] = val;
          mx = fmaxf(mx, val);
        }
      }
      mx = fmaxf(mx, __shfl_xor(mx, 16));
      mx = fmaxf(mx, __shfl_xor(mx, 32));
      float sm = 0.f;
#pragma unroll
      for (int jt = 0; jt < 4; ++jt)
#pragma unroll
        for (int r2 = 0; r2 < 4; ++r2) {
          float e = __expf(s[jt][mtc][r2] - mx);
          s[jt][mtc][r2] = e;
          sm += e;
        }
      sm += __shfl_xor(sm, 16);
      sm += __shfl_xor(sm, 32);
      float inv = 1.f / sm;
#pragma unroll
      for (int jt = 0; jt < 4; ++jt) s[jt][mtc] *= inv;
    }

    // PV in two K-halves through wave-private P buffer (4 KiB in xs region)
    unsigned char* Pb = lds + wv * 4096;  // [m][32] bf16, stride 64B
    f32x4 oacc[2][4];
#pragma unroll
    for (int dt = 0; dt < 2; ++dt)
#pragma unroll
      for (int ntc = 0; ntc < 4; ++ntc) oacc[dt][ntc] = {0.f, 0.f, 0.f, 0.f};
#pragma unroll
    for (int half = 0; half < 2; ++half) {
#pragma unroll
      for (int jt2 = 0; jt2 < 2; ++jt2) {
        int jt = 2 * half + jt2;
#pragma unroll
        for (int mtc = 0; mtc < 4; ++mtc) {
          int m = lr + 16 * mtc;
          *(unsigned long long*)(Pb + m * 64 + 32 * jt2 + 8 * lg) = pack4bf(s[jt][mtc]);
        }
      }
      bf16x8 pf[4];
#pragma unroll
      for (int ntc = 0; ntc < 4; ++ntc)
        pf[ntc] = *(const bf16x8*)(Pb + (lr + 16 * ntc) * 64 + lg * 16);
#pragma unroll
      for (int dt = 0; dt < 2; ++dt) {
        int d = lr + 16 * dt;
        bf16x8 vf = *(const bf16x8*)(vb + d * 128 + ((64 * half + 16 * lg) ^ ((d & 7) << 4)));
#pragma unroll
        for (int ntc = 0; ntc < 4; ++ntc)
          oacc[dt][ntc] = __builtin_amdgcn_mfma_f32_16x16x32_bf16(vf, pf[ntc], oacc[dt][ntc], 0, 0, 0);
      }
    }
    // ao[h][m][d] into the (consumed) k region
    unsigned char* aob = lds + 65536 + h * 4096;
#pragma unroll
    for (int dt = 0; dt < 2; ++dt)
#pragma unroll
      for (int ntc = 0; ntc < 4; ++ntc) {
        int m = lr + 16 * ntc;
        int dd0 = 16 * dt + 4 * lg;
        *(unsigned long long*)(aob + m * 64 + dd0 * 2) = pack4bf(oacc[dt][ntc]);
      }
  }
  __syncthreads();

  // ---- Phase 4: proj^T[o][m] = sum_c Wp[o][c] * ao[m][c]; coalesced fp32 stores
  {
    const unsigned char* wsP = ws + 393216;
    bf16x8 aof[4][8];
#pragma unroll
    for (int tt = 0; tt < 4; ++tt) {
      int m = lr + 16 * tt;
#pragma unroll
      for (int ks = 0; ks < 8; ++ks)
        aof[tt][ks] = *(const bf16x8*)(lds + 65536 + ks * 4096 + m * 64 + lg * 16);
    }
#pragma unroll
    for (int i = 0; i < 2; ++i) {
      const int mt = 2 * wv + i;  // 0..15 out-channel tile
      bf16x8 af[8];
#pragma unroll
      for (int ks = 0; ks < 8; ++ks)
        af[ks] = *(const bf16x8*)(wsP + (size_t)(mt * 8 + ks) * 1024 + ln * 16);
      f32x4 pb;
#pragma unroll
      for (int r2 = 0; r2 < 4; ++r2) pb[r2] = proj_b[16 * mt + 4 * lg + r2];
      const int o0 = 16 * mt + 4 * lg;
#pragma unroll
      for (int tt = 0; tt < 4; ++tt) {
        f32x4 acc = {0.f, 0.f, 0.f, 0.f};
#pragma unroll
        for (int ks = 0; ks < 8; ++ks)
          acc = __builtin_amdgcn_mfma_f32_16x16x32_bf16(af[ks], aof[tt][ks], acc, 0, 0, 0);
        int m = lr + 16 * tt;
        if (m < 49) {
          acc += pb;
          *(f32x4*)(out + ((size_t)b * 49 + m) * 256 + o0) = acc;
        }
      }
    }
  }
}

extern "C" void kernel_launch(void* const* d_in, const int* in_sizes, int n_in,
                              void* d_out, int out_size, void* d_ws, size_t ws_size,
                              hipStream_t stream) {
  const float* x = (const float*)d_in[0];
  const float* mask = (const float*)d_in[1];
  const float* qkv_w = (const float*)d_in[2];
  const float* qkv_b = (const float*)d_in[3];
  const float* proj_w = (const float*)d_in[4];
  const float* proj_b = (const float*)d_in[5];
  const float* bias_table = (const float*)d_in[6];
  unsigned char* ws = (unsigned char*)d_ws;
  float* out = (float*)d_out;

  prep_weights<<<512, 64, 0, stream>>>(qkv_w, proj_w, ws);
  winattn_main<<<4096, 512, 0, stream>>>(x, mask, qkv_b, proj_b, bias_table, ws, out);
}